// Round 1
// baseline (1620.341 us; speedup 1.0000x reference)
//
#include <hip/hip_runtime.h>
#include <stdint.h>

#define NN 100000
#define NE 1600000

typedef __attribute__((ext_vector_type(8))) short bfrag;   // 8 bf16 = 4 VGPRs
typedef __attribute__((ext_vector_type(4))) float ffrag;   // mfma accumulator

__device__ __forceinline__ uint16_t f2bf(float f) {
  uint32_t u = __float_as_uint(f);
  u += 0x7fff + ((u >> 16) & 1);   // round-to-nearest-even
  return (uint16_t)(u >> 16);
}
__device__ __forceinline__ uint32_t pack2(float a, float b) {
  return (uint32_t)f2bf(a) | ((uint32_t)f2bf(b) << 16);
}

// ---------- x (fp32) -> h (bf16, packed pairs) ----------
__global__ void k_cast_x(const float* __restrict__ x, uint32_t* __restrict__ h) {
  int n = NN * 64;
  for (int i = blockIdx.x * blockDim.x + threadIdx.x; i < n; i += gridDim.x * blockDim.x) {
    float2 v = ((const float2*)x)[i];
    h[i] = pack2(v.x, v.y);
  }
}

// ---------- pre-swizzle all 8 weight matrices into MFMA B-fragment order ----------
// wswz[m][f=t*8+ct][lane][j] = W[t*32 + (lane>>4)*8 + j][ct*16 + (lane&15)]
__global__ void k_prep_w(const float* __restrict__ Wg0, const float* __restrict__ Wg1,
                         const float* __restrict__ Wfc, uint16_t* __restrict__ wswz) {
  int idx = blockIdx.x * 256 + threadIdx.x;          // 0 .. 131071 (8 * 16384)
  int m = idx >> 14;
  int rem = idx & 16383;
  int j = rem & 7;
  int lane = (rem >> 3) & 63;
  int f = rem >> 9;                                   // t*8+ct
  int t = f >> 3, ct = f & 7;
  int k = t * 32 + (lane >> 4) * 8 + j;
  int n = ct * 16 + (lane & 15);
  const float* src = (m < 3) ? (Wg0 + m * 16384)
                   : (m < 6) ? (Wg1 + (m - 3) * 16384)
                             : (Wfc + (m - 6) * 16384);
  wswz[idx] = f2bf(src[k * 128 + n]);
}

// ---------- tiny constants: bias2 = (sum_r bg)@Wfc + bfc ; BN folded to g2,b2 ----------
__global__ void k_prep_consts(const float* __restrict__ bg0, const float* __restrict__ bg1,
                              const float* __restrict__ Wfc, const float* __restrict__ bfc,
                              const float* __restrict__ gamma, const float* __restrict__ beta,
                              const float* __restrict__ mean, const float* __restrict__ var,
                              float* __restrict__ cst) {
  int tid = threadIdx.x;              // 0..255 = l*128 + n
  int l = tid >> 7, n = tid & 127;
  const float* bg = l ? bg1 : bg0;
  float acc = bfc[l * 128 + n];
  for (int k = 0; k < 128; k++) {
    float bsum = bg[k] + bg[128 + k] + bg[256 + k];
    acc += bsum * Wfc[l * 16384 + k * 128 + n];
  }
  cst[tid] = acc;                                    // bias2
  float g = gamma[tid] * rsqrtf(var[tid] + 1e-5f);
  cst[256 + tid] = g;                                // g2
  cst[512 + tid] = beta[tid] - mean[tid] * g;        // b2
}

// ---------- degree histograms ----------
__global__ void k_degrees(const int* s0, const int* d0, const int* s1, const int* d1,
                          const int* s2, const int* d2,
                          int* __restrict__ cnt_out, int* __restrict__ cnt_in) {
  int total = 3 * NE;
  for (int i = blockIdx.x * blockDim.x + threadIdx.x; i < total; i += gridDim.x * blockDim.x) {
    int r = (i >= 2 * NE) ? 2 : (i >= NE) ? 1 : 0;
    int e = i - r * NE;
    const int* sp = (r == 0) ? s0 : (r == 1) ? s1 : s2;
    const int* dp = (r == 0) ? d0 : (r == 1) ? d1 : d2;
    atomicAdd(&cnt_out[r * NN + sp[e]], 1);
    atomicAdd(&cnt_in[r * NN + dp[e]], 1);
  }
}

// ---------- exclusive scan of in-degrees -> rowptr; also s_in = rsqrt(max(deg,1)) ----------
__global__ void k_scan(const int* __restrict__ cnt_in, int* __restrict__ rowptr,
                       float* __restrict__ s_in) {
  int r = blockIdx.x;
  const int* c = cnt_in + r * NN;
  int* rp = rowptr + r * (NN + 1);
  float* si = s_in + r * NN;
  __shared__ int wsum[16];
  __shared__ int wexcl[16];
  __shared__ int tot;
  int lane = threadIdx.x & 63;
  int wid = threadIdx.x >> 6;
  int carry = 0;
  for (int base = 0; base < NN; base += 1024) {
    int i = base + (int)threadIdx.x;
    int v = (i < NN) ? c[i] : 0;
    int x = v;
#pragma unroll
    for (int o = 1; o < 64; o <<= 1) {
      int y = __shfl_up(x, o);
      if (lane >= o) x += y;
    }
    if (lane == 63) wsum[wid] = x;
    __syncthreads();
    if (threadIdx.x < 16) {
      int wv = wsum[threadIdx.x];
      int wx = wv;
#pragma unroll
      for (int o = 1; o < 16; o <<= 1) {
        int y = __shfl_up(wx, o);
        if ((int)threadIdx.x >= o) wx += y;
      }
      wexcl[threadIdx.x] = wx - wv;
      if (threadIdx.x == 15) tot = wx;
    }
    __syncthreads();
    if (i < NN) {
      int incl = carry + wexcl[wid] + x;
      rp[i] = incl - v;
      si[i] = rsqrtf((float)(v < 1 ? 1 : v));
    }
    carry += tot;
    __syncthreads();
  }
  if (threadIdx.x == 0) rp[NN] = carry;
}

// ---------- in-place cnt_out -> s_out = rsqrt(max(deg,1)) ----------
__global__ void k_cvt_sout(int* __restrict__ cnt) {
  int n = 3 * NN;
  for (int i = blockIdx.x * blockDim.x + threadIdx.x; i < n; i += gridDim.x * blockDim.x) {
    int v = cnt[i];
    ((float*)cnt)[i] = rsqrtf((float)(v < 1 ? 1 : v));
  }
}

// ---------- CSR fill: col[rowptr[dst] + slot] = src ----------
__global__ void k_fill(const int* s0, const int* d0, const int* s1, const int* d1,
                       const int* s2, const int* d2,
                       const int* __restrict__ rowptr, int* __restrict__ fill,
                       int* __restrict__ col) {
  int total = 3 * NE;
  for (int i = blockIdx.x * blockDim.x + threadIdx.x; i < total; i += gridDim.x * blockDim.x) {
    int r = (i >= 2 * NE) ? 2 : (i >= NE) ? 1 : 0;
    int e = i - r * NE;
    const int* sp = (r == 0) ? s0 : (r == 1) ? s1 : s2;
    const int* dp = (r == 0) ? d0 : (r == 1) ? d1 : d2;
    int dst = dp[e];
    int pos = rowptr[r * (NN + 1) + dst] + atomicAdd(&fill[r * NN + dst], 1);
    col[(size_t)r * NE + pos] = sp[e];
  }
}

// ---------- aggregation: agg_r[n] = rsqrt(deg_in) * sum_e rsqrt(deg_out[src]) * h[src] ----------
// one wave per dst node; lane covers feature pair (2*lane, 2*lane+1)
__global__ void k_aggregate(const uint32_t* __restrict__ h, const int* __restrict__ rowptr,
                            const int* __restrict__ col, const float* __restrict__ s_out,
                            const float* __restrict__ s_in, uint32_t* __restrict__ agg) {
  int r = blockIdx.y;
  int node = blockIdx.x * 4 + (threadIdx.x >> 6);
  int lane = threadIdx.x & 63;
  const int* rp = rowptr + r * (NN + 1);
  int beg = rp[node], end = rp[node + 1];
  const int* cl = col + (size_t)r * NE;
  const float* so = s_out + r * NN;
  float a0 = 0.f, a1 = 0.f;
  for (int base = beg; base < end; base += 64) {
    int idx = base + lane;
    int s = 0; float w = 0.f;
    if (idx < end) { s = cl[idx]; w = so[s]; }
    int cnt = min(64, end - base);
    for (int j = 0; j < cnt; j++) {
      int ss = __shfl(s, j);
      float ww = __shfl(w, j);
      uint32_t hv = h[ss * 64 + lane];
      a0 = fmaf(__uint_as_float(hv << 16), ww, a0);
      a1 = fmaf(__uint_as_float(hv & 0xffff0000u), ww, a1);
    }
  }
  float sc = s_in[r * NN + node];
  agg[((size_t)r * NN + node) * 64 + lane] = pack2(a0 * sc, a1 * sc);
}

// ---------- P_r = agg_r @ Wg[l][r]   (bf16 MFMA, wave-held B frags) ----------
__global__ __launch_bounds__(256, 2) void k_gconv_mm(const uint32_t* __restrict__ agg,
                                                     const short* __restrict__ wswz,
                                                     int wbase, uint16_t* __restrict__ P) {
  int r = blockIdx.y;
  int lane = threadIdx.x & 63;
  int wid = threadIdx.x >> 6;
  int q = lane >> 4, n0 = lane & 15;
  const bfrag* wp = (const bfrag*)(wswz + (size_t)(wbase + r) * 16384);
  bfrag B[32];
#pragma unroll
  for (int f = 0; f < 32; f++) B[f] = wp[f * 64 + lane];
  const uint32_t* A = agg + (size_t)r * NN * 64;
  uint16_t* Pr = P + (size_t)r * NN * 128;
  const int ntiles = NN / 16;   // 6250, exact
  for (int tile = blockIdx.x * 4 + wid; tile < ntiles; tile += gridDim.x * 4) {
    int arow = tile * 16 + n0;
    bfrag a[4];
#pragma unroll
    for (int t = 0; t < 4; t++)
      a[t] = *(const bfrag*)(A + (size_t)arow * 64 + t * 16 + q * 4);
    ffrag acc[8];
#pragma unroll
    for (int ct = 0; ct < 8; ct++) {
      ffrag c = {0.f, 0.f, 0.f, 0.f};
#pragma unroll
      for (int t = 0; t < 4; t++)
        c = __builtin_amdgcn_mfma_f32_16x16x32_bf16(a[t], B[t * 8 + ct], c, 0, 0, 0);
      acc[ct] = c;
    }
    int orow = tile * 16 + q * 4;
#pragma unroll
    for (int ct = 0; ct < 8; ct++)
#pragma unroll
      for (int i = 0; i < 4; i++)
        Pr[(size_t)(orow + i) * 128 + ct * 16 + n0] = f2bf(acc[ct][i]);
  }
}

// ---------- FC: out = relu([P0|P1|P2] @ [Wfc;Wfc;Wfc] + bias2); BN folded ----------
__global__ __launch_bounds__(256, 2) void k_fc(const uint32_t* __restrict__ P,
                                               const short* __restrict__ wswz, int m,
                                               const float* __restrict__ cst, int l,
                                               uint16_t* __restrict__ hout,
                                               float* __restrict__ fout, int wf32) {
  int lane = threadIdx.x & 63;
  int wid = threadIdx.x >> 6;
  int q = lane >> 4, n0 = lane & 15;
  const bfrag* wp = (const bfrag*)(wswz + (size_t)m * 16384);
  bfrag B[32];
#pragma unroll
  for (int f = 0; f < 32; f++) B[f] = wp[f * 64 + lane];
  float bb[8], gg[8], b2v[8];
#pragma unroll
  for (int ct = 0; ct < 8; ct++) {
    int c = l * 128 + ct * 16 + n0;
    bb[ct] = cst[c];
    gg[ct] = cst[256 + c];
    b2v[ct] = cst[512 + c];
  }
  const int ntiles = NN / 16;
  for (int tile = blockIdx.x * 4 + wid; tile < ntiles; tile += gridDim.x * 4) {
    int arow = tile * 16 + n0;
    ffrag acc[8];
#pragma unroll
    for (int ct = 0; ct < 8; ct++) acc[ct] = (ffrag){0.f, 0.f, 0.f, 0.f};
    for (int rr = 0; rr < 3; rr++) {          // K=384 concat: sum over relations in-MFMA
      const uint32_t* A = P + (size_t)rr * NN * 64;
      bfrag a[4];
#pragma unroll
      for (int t = 0; t < 4; t++)
        a[t] = *(const bfrag*)(A + (size_t)arow * 64 + t * 16 + q * 4);
#pragma unroll
      for (int ct = 0; ct < 8; ct++) {
#pragma unroll
        for (int t = 0; t < 4; t++)
          acc[ct] = __builtin_amdgcn_mfma_f32_16x16x32_bf16(a[t], B[t * 8 + ct], acc[ct], 0, 0, 0);
      }
    }
    int orow = tile * 16 + q * 4;
#pragma unroll
    for (int ct = 0; ct < 8; ct++) {
#pragma unroll
      for (int i = 0; i < 4; i++) {
        float y = acc[ct][i] + bb[ct];
        y = fmaxf(y, 0.f);
        float hv = fmaf(y, gg[ct], b2v[ct]);
        size_t oi = (size_t)(orow + i) * 128 + ct * 16 + n0;
        if (wf32) fout[oi] = hv;
        else hout[oi] = f2bf(hv);
      }
    }
  }
}

extern "C" void kernel_launch(void* const* d_in, const int* in_sizes, int n_in,
                              void* d_out, int out_size, void* d_ws, size_t ws_size,
                              hipStream_t stream) {
  const float* x = (const float*)d_in[0];
  const int* s0 = (const int*)d_in[1]; const int* d0 = (const int*)d_in[2];
  const int* s1 = (const int*)d_in[3]; const int* d1 = (const int*)d_in[4];
  const int* s2 = (const int*)d_in[5]; const int* d2 = (const int*)d_in[6];
  const float* Wg0 = (const float*)d_in[7];
  const float* bg0 = (const float*)d_in[8];
  const float* Wg1 = (const float*)d_in[9];
  const float* bg1 = (const float*)d_in[10];
  const float* Wfc = (const float*)d_in[11];
  const float* bfc = (const float*)d_in[12];
  const float* gamma = (const float*)d_in[13];
  const float* beta = (const float*)d_in[14];
  const float* mean = (const float*)d_in[15];
  const float* var = (const float*)d_in[16];

  char* ws = (char*)d_ws;
  size_t off = 0;
  auto alloc = [&](size_t bytes) { size_t o = off; off = (off + bytes + 255) & ~(size_t)255; return o; };
  size_t o_sout = alloc((size_t)3 * NN * 4);          // int counts, then fp32 rsqrt in place
  size_t o_cin  = alloc((size_t)3 * NN * 4);
  size_t o_fill = alloc((size_t)3 * NN * 4);
  size_t o_sin  = alloc((size_t)3 * NN * 4);
  size_t o_rp   = alloc((size_t)3 * (NN + 1) * 4);
  size_t o_col  = alloc((size_t)3 * NE * 4);
  size_t o_wswz = alloc((size_t)131072 * 2);
  size_t o_cst  = alloc((size_t)768 * 4);
  size_t o_h    = alloc((size_t)NN * 128 * 2);
  size_t o_agg  = alloc((size_t)3 * NN * 128 * 2);
  size_t o_P    = alloc((size_t)3 * NN * 128 * 2);
  (void)ws_size; (void)in_sizes; (void)n_in; (void)out_size;   // total ~205 MB

  int* cnt_out = (int*)(ws + o_sout);
  float* s_out = (float*)(ws + o_sout);
  int* cnt_in  = (int*)(ws + o_cin);
  int* fill    = (int*)(ws + o_fill);
  float* s_in  = (float*)(ws + o_sin);
  int* rowptr  = (int*)(ws + o_rp);
  int* col     = (int*)(ws + o_col);
  uint16_t* wswz = (uint16_t*)(ws + o_wswz);
  float* cst   = (float*)(ws + o_cst);
  uint32_t* h  = (uint32_t*)(ws + o_h);
  uint32_t* agg = (uint32_t*)(ws + o_agg);
  uint16_t* P  = (uint16_t*)(ws + o_P);

  // zero the three count/fill sections (contiguous) — ws is poisoned 0xAA each call
  hipMemsetAsync(ws + o_sout, 0, o_sin - o_sout, stream);

  k_cast_x<<<2048, 256, 0, stream>>>(x, h);
  k_prep_w<<<512, 256, 0, stream>>>(Wg0, Wg1, Wfc, wswz);
  k_prep_consts<<<1, 256, 0, stream>>>(bg0, bg1, Wfc, bfc, gamma, beta, mean, var, cst);
  k_degrees<<<2048, 256, 0, stream>>>(s0, d0, s1, d1, s2, d2, cnt_out, cnt_in);
  k_scan<<<3, 1024, 0, stream>>>(cnt_in, rowptr, s_in);
  k_cvt_sout<<<1172, 256, 0, stream>>>(cnt_out);
  k_fill<<<2048, 256, 0, stream>>>(s0, d0, s1, d1, s2, d2, rowptr, fill, col);

  for (int l = 0; l < 2; l++) {
    k_aggregate<<<dim3(25000, 3), 256, 0, stream>>>(h, rowptr, col, s_out, s_in, agg);
    k_gconv_mm<<<dim3(256, 3), 256, 0, stream>>>(agg, (const short*)wswz, 3 * l, P);
    k_fc<<<256, 256, 0, stream>>>((const uint32_t*)P, (const short*)wswz, 6 + l, cst, l,
                                  (uint16_t*)h, (float*)d_out, l);
  }
}

// Round 2
// 1498.758 us; speedup vs baseline: 1.0811x; 1.0811x over previous
//
#include <hip/hip_runtime.h>
#include <stdint.h>

#define NN 100000
#define NE 1600000
#define NE4 (NE / 4)
#define NNP1 100008          // rowptr row stride, padded for int4 alignment
#define NBR 98               // scan chunks (1024 nodes) per relation
#define NB (3 * NBR)

typedef __attribute__((ext_vector_type(8))) short bfrag;   // 8 bf16 = 4 VGPRs
typedef __attribute__((ext_vector_type(4))) float ffrag;   // mfma accumulator

__device__ __forceinline__ uint16_t f2bf(float f) {
  uint32_t u = __float_as_uint(f);
  u += 0x7fff + ((u >> 16) & 1);   // round-to-nearest-even
  return (uint16_t)(u >> 16);
}
__device__ __forceinline__ uint32_t pack2(float a, float b) {
  return (uint32_t)f2bf(a) | ((uint32_t)f2bf(b) << 16);
}

// ---------- x (fp32) -> h (bf16, packed pairs) ----------
__global__ void k_cast_x(const float* __restrict__ x, uint32_t* __restrict__ h) {
  int n = NN * 64;
  for (int i = blockIdx.x * blockDim.x + threadIdx.x; i < n; i += gridDim.x * blockDim.x) {
    float2 v = ((const float2*)x)[i];
    h[i] = pack2(v.x, v.y);
  }
}

// ---------- pre-swizzle all 8 weight matrices into MFMA B-fragment order ----------
__global__ void k_prep_w(const float* __restrict__ Wg0, const float* __restrict__ Wg1,
                         const float* __restrict__ Wfc, uint16_t* __restrict__ wswz) {
  int idx = blockIdx.x * 256 + threadIdx.x;          // 0 .. 131071 (8 * 16384)
  int m = idx >> 14;
  int rem = idx & 16383;
  int j = rem & 7;
  int lane = (rem >> 3) & 63;
  int f = rem >> 9;                                   // t*8+ct
  int t = f >> 3, ct = f & 7;
  int k = t * 32 + (lane >> 4) * 8 + j;
  int n = ct * 16 + (lane & 15);
  const float* src = (m < 3) ? (Wg0 + m * 16384)
                   : (m < 6) ? (Wg1 + (m - 3) * 16384)
                             : (Wfc + (m - 6) * 16384);
  wswz[idx] = f2bf(src[k * 128 + n]);
}

// ---------- tiny constants: bias2 = (sum_r bg)@Wfc + bfc ; BN folded to g2,b2 ----------
__global__ void k_prep_consts(const float* __restrict__ bg0, const float* __restrict__ bg1,
                              const float* __restrict__ Wfc, const float* __restrict__ bfc,
                              const float* __restrict__ gamma, const float* __restrict__ beta,
                              const float* __restrict__ mean, const float* __restrict__ var,
                              float* __restrict__ cst) {
  int tid = threadIdx.x;              // 0..255 = l*128 + n
  int l = tid >> 7, n = tid & 127;
  const float* bg = l ? bg1 : bg0;
  float acc = bfc[l * 128 + n];
  for (int k = 0; k < 128; k++) {
    float bsum = bg[k] + bg[128 + k] + bg[256 + k];
    acc += bsum * Wfc[l * 16384 + k * 128 + n];
  }
  cst[tid] = acc;                                    // bias2
  float g = gamma[tid] * rsqrtf(var[tid] + 1e-5f);
  cst[256 + tid] = g;                                // g2
  cst[512 + tid] = beta[tid] - mean[tid] * g;        // b2
}

// ---------- in-degree histogram, u8-packed counters (4 nodes per u32 word) ----------
__global__ void k_deg_in(const int* __restrict__ d0, const int* __restrict__ d1,
                         const int* __restrict__ d2, uint32_t* __restrict__ cnt) {
  int total = 3 * NE4;
  for (int i = blockIdx.x * blockDim.x + threadIdx.x; i < total; i += gridDim.x * blockDim.x) {
    int r = (i >= 2 * NE4) ? 2 : (i >= NE4) ? 1 : 0;
    int e4 = i - r * NE4;
    const int4* dp = (const int4*)((r == 0) ? d0 : (r == 1) ? d1 : d2);
    int4 d = dp[e4];
    int base = r * NN;
#define DEG1(n) { int idx = base + (n); atomicAdd(&cnt[idx >> 2], 1u << ((idx & 3) << 3)); }
    DEG1(d.x) DEG1(d.y) DEG1(d.z) DEG1(d.w)
#undef DEG1
  }
}

// ---------- scan phase 1: per-chunk (1024 nodes) byte sums ----------
__global__ void k_bsum(const uint32_t* __restrict__ cw, int* __restrict__ bsum) {
  int b = blockIdx.x;
  int r = b / NBR, c = b % NBR;
  int t = threadIdx.x;                        // 0..255
  int node = (c << 10) + (t << 2);
  uint32_t v = (node < NN) ? cw[((r * NN) >> 2) + (c << 8) + t] : 0u;
  int s = (v & 0xff) + ((v >> 8) & 0xff) + ((v >> 16) & 0xff) + (v >> 24);
  int lane = t & 63, wid = t >> 6;
#pragma unroll
  for (int o = 1; o < 64; o <<= 1) s += __shfl_xor(s, o);
  __shared__ int wsum[4];
  if (lane == 0) wsum[wid] = s;
  __syncthreads();
  if (t == 0) bsum[b] = wsum[0] + wsum[1] + wsum[2] + wsum[3];
}

// ---------- scan phase 2: 1-block exclusive scan of the 294 chunk sums ----------
__global__ void k_scan_bsum(const int* __restrict__ bsum, int* __restrict__ bexcl,
                            int* __restrict__ rowptr) {
  int t = threadIdx.x;                        // 512 threads
  int lane = t & 63, wid = t >> 6;
  int v = (t < NB) ? bsum[t] : 0;
  int x = v;
#pragma unroll
  for (int o = 1; o < 64; o <<= 1) { int y = __shfl_up(x, o); if (lane >= o) x += y; }
  __shared__ int wsum[8];
  if (lane == 63) wsum[wid] = x;
  __syncthreads();
  int woff = 0;
  for (int i = 0; i < wid; i++) woff += wsum[i];
  int incl = woff + x;
  __shared__ int E[NB];
  if (t < NB) E[t] = incl - v;               // global exclusive
  __syncthreads();
  if (t < NB) bexcl[t] = E[t] - E[(t / NBR) * NBR];   // relation-local exclusive
  if (t == NBR - 1 || t == 2 * NBR - 1 || t == 3 * NBR - 1) {
    int r = t / NBR;
    rowptr[r * NNP1 + NN] = incl - E[r * NBR];        // per-relation edge total
  }
}

// ---------- scan phase 3: final rowptr + s_in ----------
__global__ void k_scan_final(const uint32_t* __restrict__ cw, const int* __restrict__ bexcl,
                             int* __restrict__ rowptr, float* __restrict__ s_in) {
  int b = blockIdx.x;
  int r = b / NBR, c = b % NBR;
  int t = threadIdx.x;
  int lane = t & 63, wid = t >> 6;
  int node = (c << 10) + (t << 2);
  uint32_t v = (node < NN) ? cw[((r * NN) >> 2) + (c << 8) + t] : 0u;
  int b0 = v & 0xff, b1 = (v >> 8) & 0xff, b2 = (v >> 16) & 0xff, b3 = v >> 24;
  int s = b0 + b1 + b2 + b3;
  int x = s;
#pragma unroll
  for (int o = 1; o < 64; o <<= 1) { int y = __shfl_up(x, o); if (lane >= o) x += y; }
  __shared__ int wsum[4];
  if (lane == 63) wsum[wid] = x;
  __syncthreads();
  int woff = 0;
  for (int i = 0; i < wid; i++) woff += wsum[i];
  if (node < NN) {
    int p0 = bexcl[b] + woff + x - s;
    int p1 = p0 + b0, p2 = p1 + b1, p3 = p2 + b2;
    ((int4*)(rowptr + r * NNP1 + node))[0] = make_int4(p0, p1, p2, p3);
    float4 si;
    si.x = rsqrtf((float)(b0 < 1 ? 1 : b0));
    si.y = rsqrtf((float)(b1 < 1 ? 1 : b1));
    si.z = rsqrtf((float)(b2 < 1 ? 1 : b2));
    si.w = rsqrtf((float)(b3 < 1 ? 1 : b3));
    ((float4*)(s_in + r * NN + node))[0] = si;
  }
}

// ---------- CSR fill (u8-packed slot claim) + out-degree histogram ----------
__global__ void k_fill(const int* __restrict__ s0, const int* __restrict__ d0,
                       const int* __restrict__ s1, const int* __restrict__ d1,
                       const int* __restrict__ s2, const int* __restrict__ d2,
                       const int* __restrict__ rowptr, uint32_t* __restrict__ fill,
                       uint32_t* __restrict__ cnt_out, int* __restrict__ col) {
  int total = 3 * NE4;
  for (int i = blockIdx.x * blockDim.x + threadIdx.x; i < total; i += gridDim.x * blockDim.x) {
    int r = (i >= 2 * NE4) ? 2 : (i >= NE4) ? 1 : 0;
    int e4 = i - r * NE4;
    const int4* sp = (const int4*)((r == 0) ? s0 : (r == 1) ? s1 : s2);
    const int4* dp = (const int4*)((r == 0) ? d0 : (r == 1) ? d1 : d2);
    int4 sv = sp[e4];
    int4 dv = dp[e4];
    const int* rp = rowptr + r * NNP1;
    int* cl = col + r * NE;
    int base = r * NN;
#define FILL1(S, D) { \
    int idx = base + (D); int sh = (idx & 3) << 3; \
    uint32_t old = atomicAdd(&fill[idx >> 2], 1u << sh); \
    int slot = (old >> sh) & 0xff; \
    cl[rp[D] + slot] = (S); \
    int oidx = base + (S); \
    atomicAdd(&cnt_out[oidx >> 2], 1u << ((oidx & 3) << 3)); }
    FILL1(sv.x, dv.x) FILL1(sv.y, dv.y) FILL1(sv.z, dv.z) FILL1(sv.w, dv.w)
#undef FILL1
  }
}

// ---------- u8-packed out-degrees -> s_out = rsqrt(max(deg,1)) fp32 ----------
__global__ void k_cvt_sout(const uint32_t* __restrict__ cw, float* __restrict__ s_out) {
  int i = blockIdx.x * 256 + threadIdx.x;    // word index, 75000 words
  if (i < 3 * NN / 4) {
    uint32_t v = cw[i];
    int b0 = v & 0xff, b1 = (v >> 8) & 0xff, b2 = (v >> 16) & 0xff, b3 = v >> 24;
    float4 o;
    o.x = rsqrtf((float)(b0 < 1 ? 1 : b0));
    o.y = rsqrtf((float)(b1 < 1 ? 1 : b1));
    o.z = rsqrtf((float)(b2 < 1 ? 1 : b2));
    o.w = rsqrtf((float)(b3 < 1 ? 1 : b3));
    ((float4*)s_out)[i] = o;
  }
}

// ---------- aggregation: agg_r[n] = rsqrt(deg_in) * sum_e rsqrt(deg_out[src]) * h[src] ----------
__global__ void k_aggregate(const uint32_t* __restrict__ h, const int* __restrict__ rowptr,
                            const int* __restrict__ col, const float* __restrict__ s_out,
                            const float* __restrict__ s_in, uint32_t* __restrict__ agg) {
  int r = blockIdx.y;
  int node = blockIdx.x * 4 + (threadIdx.x >> 6);
  int lane = threadIdx.x & 63;
  const int* rp = rowptr + r * NNP1;
  int beg = rp[node], end = rp[node + 1];
  const int* cl = col + (size_t)r * NE;
  const float* so = s_out + r * NN;
  float a0 = 0.f, a1 = 0.f;
  for (int base = beg; base < end; base += 64) {
    int idx = base + lane;
    int s = 0; float w = 0.f;
    if (idx < end) { s = cl[idx]; w = so[s]; }
    int cnt = min(64, end - base);
    for (int j = 0; j < cnt; j++) {
      int ss = __shfl(s, j);
      float ww = __shfl(w, j);
      uint32_t hv = h[ss * 64 + lane];
      a0 = fmaf(__uint_as_float(hv << 16), ww, a0);
      a1 = fmaf(__uint_as_float(hv & 0xffff0000u), ww, a1);
    }
  }
  float sc = s_in[r * NN + node];
  agg[((size_t)r * NN + node) * 64 + lane] = pack2(a0 * sc, a1 * sc);
}

// ---------- P_r = agg_r @ Wg[l][r]   (bf16 MFMA, wave-held B frags) ----------
__global__ __launch_bounds__(256, 2) void k_gconv_mm(const uint32_t* __restrict__ agg,
                                                     const short* __restrict__ wswz,
                                                     int wbase, uint16_t* __restrict__ P) {
  int r = blockIdx.y;
  int lane = threadIdx.x & 63;
  int wid = threadIdx.x >> 6;
  int q = lane >> 4, n0 = lane & 15;
  const bfrag* wp = (const bfrag*)(wswz + (size_t)(wbase + r) * 16384);
  bfrag B[32];
#pragma unroll
  for (int f = 0; f < 32; f++) B[f] = wp[f * 64 + lane];
  const uint32_t* A = agg + (size_t)r * NN * 64;
  uint16_t* Pr = P + (size_t)r * NN * 128;
  const int ntiles = NN / 16;   // 6250, exact
  for (int tile = blockIdx.x * 4 + wid; tile < ntiles; tile += gridDim.x * 4) {
    int arow = tile * 16 + n0;
    bfrag a[4];
#pragma unroll
    for (int t = 0; t < 4; t++)
      a[t] = *(const bfrag*)(A + (size_t)arow * 64 + t * 16 + q * 4);
    ffrag acc[8];
#pragma unroll
    for (int ct = 0; ct < 8; ct++) {
      ffrag c = {0.f, 0.f, 0.f, 0.f};
#pragma unroll
      for (int t = 0; t < 4; t++)
        c = __builtin_amdgcn_mfma_f32_16x16x32_bf16(a[t], B[t * 8 + ct], c, 0, 0, 0);
      acc[ct] = c;
    }
    int orow = tile * 16 + q * 4;
#pragma unroll
    for (int ct = 0; ct < 8; ct++)
#pragma unroll
      for (int i = 0; i < 4; i++)
        Pr[(size_t)(orow + i) * 128 + ct * 16 + n0] = f2bf(acc[ct][i]);
  }
}

// ---------- FC: out = relu([P0|P1|P2] @ [Wfc;Wfc;Wfc] + bias2); BN folded ----------
__global__ __launch_bounds__(256, 2) void k_fc(const uint32_t* __restrict__ P,
                                               const short* __restrict__ wswz, int m,
                                               const float* __restrict__ cst, int l,
                                               uint16_t* __restrict__ hout,
                                               float* __restrict__ fout, int wf32) {
  int lane = threadIdx.x & 63;
  int wid = threadIdx.x >> 6;
  int q = lane >> 4, n0 = lane & 15;
  const bfrag* wp = (const bfrag*)(wswz + (size_t)m * 16384);
  bfrag B[32];
#pragma unroll
  for (int f = 0; f < 32; f++) B[f] = wp[f * 64 + lane];
  float bb[8], gg[8], b2v[8];
#pragma unroll
  for (int ct = 0; ct < 8; ct++) {
    int c = l * 128 + ct * 16 + n0;
    bb[ct] = cst[c];
    gg[ct] = cst[256 + c];
    b2v[ct] = cst[512 + c];
  }
  const int ntiles = NN / 16;
  for (int tile = blockIdx.x * 4 + wid; tile < ntiles; tile += gridDim.x * 4) {
    int arow = tile * 16 + n0;
    ffrag acc[8];
#pragma unroll
    for (int ct = 0; ct < 8; ct++) acc[ct] = (ffrag){0.f, 0.f, 0.f, 0.f};
    for (int rr = 0; rr < 3; rr++) {          // K=384 concat: sum over relations in-MFMA
      const uint32_t* A = P + (size_t)rr * NN * 64;
      bfrag a[4];
#pragma unroll
      for (int t = 0; t < 4; t++)
        a[t] = *(const bfrag*)(A + (size_t)arow * 64 + t * 16 + q * 4);
#pragma unroll
      for (int ct = 0; ct < 8; ct++) {
#pragma unroll
        for (int t = 0; t < 4; t++)
          acc[ct] = __builtin_amdgcn_mfma_f32_16x16x32_bf16(a[t], B[t * 8 + ct], acc[ct], 0, 0, 0);
      }
    }
    int orow = tile * 16 + q * 4;
#pragma unroll
    for (int ct = 0; ct < 8; ct++) {
#pragma unroll
      for (int i = 0; i < 4; i++) {
        float y = acc[ct][i] + bb[ct];
        y = fmaxf(y, 0.f);
        float hv = fmaf(y, gg[ct], b2v[ct]);
        size_t oi = (size_t)(orow + i) * 128 + ct * 16 + n0;
        if (wf32) fout[oi] = hv;
        else hout[oi] = f2bf(hv);
      }
    }
  }
}

extern "C" void kernel_launch(void* const* d_in, const int* in_sizes, int n_in,
                              void* d_out, int out_size, void* d_ws, size_t ws_size,
                              hipStream_t stream) {
  const float* x = (const float*)d_in[0];
  const int* s0 = (const int*)d_in[1]; const int* d0 = (const int*)d_in[2];
  const int* s1 = (const int*)d_in[3]; const int* d1 = (const int*)d_in[4];
  const int* s2 = (const int*)d_in[5]; const int* d2 = (const int*)d_in[6];
  const float* Wg0 = (const float*)d_in[7];
  const float* bg0 = (const float*)d_in[8];
  const float* Wg1 = (const float*)d_in[9];
  const float* bg1 = (const float*)d_in[10];
  const float* Wfc = (const float*)d_in[11];
  const float* bfc = (const float*)d_in[12];
  const float* gamma = (const float*)d_in[13];
  const float* beta = (const float*)d_in[14];
  const float* mean = (const float*)d_in[15];
  const float* var = (const float*)d_in[16];

  char* ws = (char*)d_ws;
  size_t off = 0;
  auto alloc = [&](size_t bytes) { size_t o = off; off = (off + bytes + 255) & ~(size_t)255; return o; };
  size_t o_cin  = alloc((size_t)3 * NN);              // u8-packed in-deg
  size_t o_cout = alloc((size_t)3 * NN);              // u8-packed out-deg
  size_t o_fill = alloc((size_t)3 * NN);              // u8-packed fill slots
  size_t o_sin  = alloc((size_t)3 * NN * 4);
  size_t o_sout = alloc((size_t)3 * NN * 4);
  size_t o_rp   = alloc((size_t)3 * NNP1 * 4);
  size_t o_bsum = alloc((size_t)NB * 4);
  size_t o_bexc = alloc((size_t)NB * 4);
  size_t o_col  = alloc((size_t)3 * NE * 4);
  size_t o_wswz = alloc((size_t)131072 * 2);
  size_t o_cst  = alloc((size_t)768 * 4);
  size_t o_h    = alloc((size_t)NN * 128 * 2);
  size_t o_agg  = alloc((size_t)3 * NN * 128 * 2);
  size_t o_P    = alloc((size_t)3 * NN * 128 * 2);
  (void)ws_size; (void)in_sizes; (void)n_in; (void)out_size;

  uint32_t* cnt_in  = (uint32_t*)(ws + o_cin);
  uint32_t* cnt_out = (uint32_t*)(ws + o_cout);
  uint32_t* fill    = (uint32_t*)(ws + o_fill);
  float* s_in  = (float*)(ws + o_sin);
  float* s_out = (float*)(ws + o_sout);
  int* rowptr  = (int*)(ws + o_rp);
  int* bsum    = (int*)(ws + o_bsum);
  int* bexcl   = (int*)(ws + o_bexc);
  int* col     = (int*)(ws + o_col);
  uint16_t* wswz = (uint16_t*)(ws + o_wswz);
  float* cst   = (float*)(ws + o_cst);
  uint32_t* h  = (uint32_t*)(ws + o_h);
  uint32_t* agg = (uint32_t*)(ws + o_agg);
  uint16_t* P  = (uint16_t*)(ws + o_P);

  // zero the three packed counter arrays (contiguous)
  hipMemsetAsync(ws + o_cin, 0, o_sin - o_cin, stream);

  k_cast_x<<<2048, 256, 0, stream>>>(x, h);
  k_prep_w<<<512, 256, 0, stream>>>(Wg0, Wg1, Wfc, wswz);
  k_prep_consts<<<1, 256, 0, stream>>>(bg0, bg1, Wfc, bfc, gamma, beta, mean, var, cst);
  k_deg_in<<<1536, 256, 0, stream>>>(d0, d1, d2, cnt_in);
  k_bsum<<<NB, 256, 0, stream>>>(cnt_in, bsum);
  k_scan_bsum<<<1, 512, 0, stream>>>(bsum, bexcl, rowptr);
  k_scan_final<<<NB, 256, 0, stream>>>(cnt_in, bexcl, rowptr, s_in);
  k_fill<<<1536, 256, 0, stream>>>(s0, d0, s1, d1, s2, d2, rowptr, fill, cnt_out, col);
  k_cvt_sout<<<294, 256, 0, stream>>>(cnt_out, s_out);

  for (int l = 0; l < 2; l++) {
    k_aggregate<<<dim3(25000, 3), 256, 0, stream>>>(h, rowptr, col, s_out, s_in, agg);
    k_gconv_mm<<<dim3(256, 3), 256, 0, stream>>>(agg, (const short*)wswz, 3 * l, P);
    k_fc<<<256, 256, 0, stream>>>((const uint32_t*)P, (const short*)wswz, 6 + l, cst, l,
                                  (uint16_t*)h, (float*)d_out, l);
  }
}

// Round 3
// 1028.117 us; speedup vs baseline: 1.5760x; 1.4578x over previous
//
#include <hip/hip_runtime.h>
#include <stdint.h>

#define NN 100000
#define NE 1600000
#define NE4 (NE / 4)
#define NNP1 100008          // rowptr row stride, padded for int4 alignment
#define NBK 196              // node buckets of 512 (100000 -> 196)
#define NSL 64               // edge slices (blocks) per relation for build

typedef __attribute__((ext_vector_type(8))) short bfrag;   // 8 bf16 = 4 VGPRs
typedef __attribute__((ext_vector_type(4))) float ffrag;   // mfma accumulator

__device__ __forceinline__ uint16_t f2bf(float f) {
  uint32_t u = __float_as_uint(f);
  u += 0x7fff + ((u >> 16) & 1);   // round-to-nearest-even
  return (uint16_t)(u >> 16);
}
__device__ __forceinline__ uint32_t pack2(float a, float b) {
  return (uint32_t)f2bf(a) | ((uint32_t)f2bf(b) << 16);
}

// ---------- x (fp32) -> h (bf16, packed pairs) ----------
__global__ void k_cast_x(const float* __restrict__ x, uint32_t* __restrict__ h) {
  int n = NN * 64;
  for (int i = blockIdx.x * blockDim.x + threadIdx.x; i < n; i += gridDim.x * blockDim.x) {
    float2 v = ((const float2*)x)[i];
    h[i] = pack2(v.x, v.y);
  }
}

// ---------- pre-swizzle all 8 weight matrices into MFMA B-fragment order ----------
__global__ void k_prep_w(const float* __restrict__ Wg0, const float* __restrict__ Wg1,
                         const float* __restrict__ Wfc, uint16_t* __restrict__ wswz) {
  int idx = blockIdx.x * 256 + threadIdx.x;          // 0 .. 131071 (8 * 16384)
  int m = idx >> 14;
  int rem = idx & 16383;
  int j = rem & 7;
  int lane = (rem >> 3) & 63;
  int f = rem >> 9;                                   // t*8+ct
  int t = f >> 3, ct = f & 7;
  int k = t * 32 + (lane >> 4) * 8 + j;
  int n = ct * 16 + (lane & 15);
  const float* src = (m < 3) ? (Wg0 + m * 16384)
                   : (m < 6) ? (Wg1 + (m - 3) * 16384)
                             : (Wfc + (m - 6) * 16384);
  wswz[idx] = f2bf(src[k * 128 + n]);
}

// ---------- tiny constants: bias2 = (sum_r bg)@Wfc + bfc ; BN folded to g2,b2 ----------
__global__ void k_prep_consts(const float* __restrict__ bg0, const float* __restrict__ bg1,
                              const float* __restrict__ Wfc, const float* __restrict__ bfc,
                              const float* __restrict__ gamma, const float* __restrict__ beta,
                              const float* __restrict__ mean, const float* __restrict__ var,
                              float* __restrict__ cst) {
  int tid = threadIdx.x;              // 0..255 = l*128 + n
  int l = tid >> 7, n = tid & 127;
  const float* bg = l ? bg1 : bg0;
  float acc = bfc[l * 128 + n];
  for (int k = 0; k < 128; k++) {
    float bsum = bg[k] + bg[128 + k] + bg[256 + k];
    acc += bsum * Wfc[l * 16384 + k * 128 + n];
  }
  cst[tid] = acc;                                    // bias2
  float g = gamma[tid] * rsqrtf(var[tid] + 1e-5f);
  cst[256 + tid] = g;                                // g2
  cst[512 + tid] = beta[tid] - mean[tid] * g;        // b2
}

// ---------- build 1: per-slice LDS bucket histograms, tiny global merge ----------
// bh layout: [seg][196], seg = r (dst side) / 3+r (src side)
__global__ void k_bhist(const int* __restrict__ s0, const int* __restrict__ s1,
                        const int* __restrict__ s2, const int* __restrict__ d0,
                        const int* __restrict__ d1, const int* __restrict__ d2,
                        uint32_t* __restrict__ bh) {
  int r = blockIdx.y, blk = blockIdx.x, t = threadIdx.x;
  __shared__ uint32_t hD[NBK], hS[NBK];
  for (int i = t; i < NBK; i += 256) { hD[i] = 0; hS[i] = 0; }
  __syncthreads();
  const int4* sp = (const int4*)((r == 0) ? s0 : (r == 1) ? s1 : s2);
  const int4* dp = (const int4*)((r == 0) ? d0 : (r == 1) ? d1 : d2);
  int base = blk * (NE4 / NSL);
  for (int i = t; i < NE4 / NSL; i += 256) {
    int4 s = sp[base + i];
    int4 d = dp[base + i];
    atomicAdd(&hD[d.x >> 9], 1u); atomicAdd(&hD[d.y >> 9], 1u);
    atomicAdd(&hD[d.z >> 9], 1u); atomicAdd(&hD[d.w >> 9], 1u);
    atomicAdd(&hS[s.x >> 9], 1u); atomicAdd(&hS[s.y >> 9], 1u);
    atomicAdd(&hS[s.z >> 9], 1u); atomicAdd(&hS[s.w >> 9], 1u);
  }
  __syncthreads();
  for (int i = t; i < NBK; i += 256) {
    if (hD[i]) atomicAdd(&bh[r * NBK + i], hD[i]);
    if (hS[i]) atomicAdd(&bh[(3 + r) * NBK + i], hS[i]);
  }
}

// ---------- build 2: exclusive scan of each segment's 196 bucket counts ----------
__global__ void k_bscan(const uint32_t* __restrict__ bh, int* __restrict__ bases,
                        uint32_t* __restrict__ cur, int* __restrict__ rowptr) {
  int seg = blockIdx.x, t = threadIdx.x;     // 256 threads
  int lane = t & 63, wid = t >> 6;
  int v = (t < NBK) ? (int)bh[seg * NBK + t] : 0;
  int x = v;
#pragma unroll
  for (int o = 1; o < 64; o <<= 1) { int y = __shfl_up(x, o); if (lane >= o) x += y; }
  __shared__ int ws[4];
  if (lane == 63) ws[wid] = x;
  __syncthreads();
  int woff = 0;
  for (int i = 0; i < wid; i++) woff += ws[i];
  int incl = woff + x, excl = incl - v;
  if (t < NBK) { bases[seg * (NBK + 1) + t] = excl; cur[seg * NBK + t] = (uint32_t)excl; }
  if (t == 255) bases[seg * (NBK + 1) + NBK] = incl;   // = NE
  if (seg < 3 && t == 0) rowptr[seg * NNP1 + NN] = NE;
}

// ---------- build 3: scatter edges into buckets (block-chunk claims, LDS cursors) ----------
// pairs[pos] = (dst&511)<<17 | src ; srcs[pos] = src&511 (u16)
__global__ void k_bscatter(const int* __restrict__ s0, const int* __restrict__ s1,
                           const int* __restrict__ s2, const int* __restrict__ d0,
                           const int* __restrict__ d1, const int* __restrict__ d2,
                           uint32_t* __restrict__ cur, uint32_t* __restrict__ pairs,
                           uint16_t* __restrict__ srcs) {
  int r = blockIdx.y, blk = blockIdx.x, t = threadIdx.x;
  __shared__ uint32_t hD[NBK], hS[NBK];
  for (int i = t; i < NBK; i += 256) { hD[i] = 0; hS[i] = 0; }
  __syncthreads();
  const int4* sp = (const int4*)((r == 0) ? s0 : (r == 1) ? s1 : s2);
  const int4* dp = (const int4*)((r == 0) ? d0 : (r == 1) ? d1 : d2);
  int base = blk * (NE4 / NSL);
  for (int i = t; i < NE4 / NSL; i += 256) {
    int4 s = sp[base + i];
    int4 d = dp[base + i];
    atomicAdd(&hD[d.x >> 9], 1u); atomicAdd(&hD[d.y >> 9], 1u);
    atomicAdd(&hD[d.z >> 9], 1u); atomicAdd(&hD[d.w >> 9], 1u);
    atomicAdd(&hS[s.x >> 9], 1u); atomicAdd(&hS[s.y >> 9], 1u);
    atomicAdd(&hS[s.z >> 9], 1u); atomicAdd(&hS[s.w >> 9], 1u);
  }
  __syncthreads();
  // claim one contiguous chunk per bucket; repurpose hist as running global cursor
  for (int i = t; i < NBK; i += 256) {
    hD[i] = atomicAdd(&cur[r * NBK + i], hD[i]);
    hS[i] = atomicAdd(&cur[(3 + r) * NBK + i], hS[i]);
  }
  __syncthreads();
  uint32_t* pr = pairs + (size_t)r * NE;
  uint16_t* sr = srcs + (size_t)r * NE;
#define SCAT1(S, D) { \
    uint32_t p = atomicAdd(&hD[(D) >> 9], 1u); \
    pr[p] = (uint32_t)(((D) & 511) << 17) | (uint32_t)(S); \
    uint32_t q = atomicAdd(&hS[(S) >> 9], 1u); \
    sr[q] = (uint16_t)((S) & 511); }
  for (int i = t; i < NE4 / NSL; i += 256) {
    int4 s = sp[base + i];
    int4 d = dp[base + i];
    SCAT1(s.x, d.x) SCAT1(s.y, d.y) SCAT1(s.z, d.z) SCAT1(s.w, d.w)
  }
#undef SCAT1
}

// ---------- build 4: per-bucket CSR (rowptr, s_in, col) ----------
__global__ void k_bucket_csr(const uint32_t* __restrict__ pairs, const int* __restrict__ bases,
                             int* __restrict__ rowptr, float* __restrict__ s_in,
                             int* __restrict__ col) {
  int b = blockIdx.x, r = blockIdx.y, t = threadIdx.x;
  int node0 = b << 9;
  int nc = min(512, NN - node0);
  int rb = bases[r * (NBK + 1) + b];
  int m = bases[r * (NBK + 1) + b + 1] - rb;
  __shared__ int cnt[512];
  __shared__ int exc[512];
  __shared__ int ws[4];
  cnt[t] = 0; cnt[t + 256] = 0;
  __syncthreads();
  const uint32_t* pp = pairs + (size_t)r * NE + rb;
  for (int i = t; i < m; i += 256) atomicAdd(&cnt[pp[i] >> 17], 1);
  __syncthreads();
  // exclusive scan of 512 counters, 2 per thread
  int v0 = cnt[2 * t], v1 = cnt[2 * t + 1];
  int s = v0 + v1, x = s;
  int lane = t & 63, wid = t >> 6;
#pragma unroll
  for (int o = 1; o < 64; o <<= 1) { int y = __shfl_up(x, o); if (lane >= o) x += y; }
  if (lane == 63) ws[wid] = x;
  __syncthreads();
  int woff = 0;
  for (int i = 0; i < wid; i++) woff += ws[i];
  int e0 = woff + x - s;
  exc[2 * t] = e0;
  exc[2 * t + 1] = e0 + v0;
  __syncthreads();
  for (int i = t; i < nc; i += 256) {
    rowptr[r * NNP1 + node0 + i] = rb + exc[i];
    s_in[r * NN + node0 + i] = rsqrtf((float)(cnt[i] < 1 ? 1 : cnt[i]));
  }
  __syncthreads();
  int* cl = col + (size_t)r * NE + rb;
  for (int i = t; i < m; i += 256) {
    uint32_t e = pp[i];
    int p = atomicAdd(&exc[e >> 17], 1);
    cl[p] = (int)(e & 0x1FFFF);
  }
}

// ---------- build 5: per-bucket out-degree -> s_out ----------
__global__ void k_bucket_sout(const uint16_t* __restrict__ srcs, const int* __restrict__ bases,
                              float* __restrict__ s_out) {
  int b = blockIdx.x, r = blockIdx.y, t = threadIdx.x;
  int node0 = b << 9;
  int nc = min(512, NN - node0);
  int rb = bases[(3 + r) * (NBK + 1) + b];
  int m = bases[(3 + r) * (NBK + 1) + b + 1] - rb;
  __shared__ int cnt[512];
  cnt[t] = 0; cnt[t + 256] = 0;
  __syncthreads();
  const uint16_t* pp = srcs + (size_t)r * NE + rb;
  for (int i = t; i < m; i += 256) atomicAdd(&cnt[pp[i]], 1);
  __syncthreads();
  for (int i = t; i < nc; i += 256)
    s_out[r * NN + node0 + i] = rsqrtf((float)(cnt[i] < 1 ? 1 : cnt[i]));
}

// ---------- aggregation: agg_r[n] = rsqrt(deg_in) * sum_e rsqrt(deg_out[src]) * h[src] ----------
__global__ void k_aggregate(const uint32_t* __restrict__ h, const int* __restrict__ rowptr,
                            const int* __restrict__ col, const float* __restrict__ s_out,
                            const float* __restrict__ s_in, uint32_t* __restrict__ agg) {
  int r = blockIdx.y;
  int node = blockIdx.x * 4 + (threadIdx.x >> 6);
  int lane = threadIdx.x & 63;
  const int* rp = rowptr + r * NNP1;
  int beg = rp[node], end = rp[node + 1];
  const int* cl = col + (size_t)r * NE;
  const float* so = s_out + r * NN;
  float a0 = 0.f, a1 = 0.f;
  for (int base = beg; base < end; base += 64) {
    int idx = base + lane;
    int s = 0; float w = 0.f;
    if (idx < end) { s = cl[idx]; w = so[s]; }
    int cnt = min(64, end - base);
    for (int j = 0; j < cnt; j++) {
      int ss = __shfl(s, j);
      float ww = __shfl(w, j);
      uint32_t hv = h[ss * 64 + lane];
      a0 = fmaf(__uint_as_float(hv << 16), ww, a0);
      a1 = fmaf(__uint_as_float(hv & 0xffff0000u), ww, a1);
    }
  }
  float sc = s_in[r * NN + node];
  agg[((size_t)r * NN + node) * 64 + lane] = pack2(a0 * sc, a1 * sc);
}

// ---------- P_r = agg_r @ Wg[l][r]   (bf16 MFMA, wave-held B frags) ----------
__global__ __launch_bounds__(256, 2) void k_gconv_mm(const uint32_t* __restrict__ agg,
                                                     const short* __restrict__ wswz,
                                                     int wbase, uint16_t* __restrict__ P) {
  int r = blockIdx.y;
  int lane = threadIdx.x & 63;
  int wid = threadIdx.x >> 6;
  int q = lane >> 4, n0 = lane & 15;
  const bfrag* wp = (const bfrag*)(wswz + (size_t)(wbase + r) * 16384);
  bfrag B[32];
#pragma unroll
  for (int f = 0; f < 32; f++) B[f] = wp[f * 64 + lane];
  const uint32_t* A = agg + (size_t)r * NN * 64;
  uint16_t* Pr = P + (size_t)r * NN * 128;
  const int ntiles = NN / 16;   // 6250, exact
  for (int tile = blockIdx.x * 4 + wid; tile < ntiles; tile += gridDim.x * 4) {
    int arow = tile * 16 + n0;
    bfrag a[4];
#pragma unroll
    for (int t = 0; t < 4; t++)
      a[t] = *(const bfrag*)(A + (size_t)arow * 64 + t * 16 + q * 4);
    ffrag acc[8];
#pragma unroll
    for (int ct = 0; ct < 8; ct++) {
      ffrag c = {0.f, 0.f, 0.f, 0.f};
#pragma unroll
      for (int t = 0; t < 4; t++)
        c = __builtin_amdgcn_mfma_f32_16x16x32_bf16(a[t], B[t * 8 + ct], c, 0, 0, 0);
      acc[ct] = c;
    }
    int orow = tile * 16 + q * 4;
#pragma unroll
    for (int ct = 0; ct < 8; ct++)
#pragma unroll
      for (int i = 0; i < 4; i++)
        Pr[(size_t)(orow + i) * 128 + ct * 16 + n0] = f2bf(acc[ct][i]);
  }
}

// ---------- FC: out = relu([P0|P1|P2] @ [Wfc;Wfc;Wfc] + bias2); BN folded ----------
__global__ __launch_bounds__(256, 2) void k_fc(const uint32_t* __restrict__ P,
                                               const short* __restrict__ wswz, int m,
                                               const float* __restrict__ cst, int l,
                                               uint16_t* __restrict__ hout,
                                               float* __restrict__ fout, int wf32) {
  int lane = threadIdx.x & 63;
  int wid = threadIdx.x >> 6;
  int q = lane >> 4, n0 = lane & 15;
  const bfrag* wp = (const bfrag*)(wswz + (size_t)m * 16384);
  bfrag B[32];
#pragma unroll
  for (int f = 0; f < 32; f++) B[f] = wp[f * 64 + lane];
  float bb[8], gg[8], b2v[8];
#pragma unroll
  for (int ct = 0; ct < 8; ct++) {
    int c = l * 128 + ct * 16 + n0;
    bb[ct] = cst[c];
    gg[ct] = cst[256 + c];
    b2v[ct] = cst[512 + c];
  }
  const int ntiles = NN / 16;
  for (int tile = blockIdx.x * 4 + wid; tile < ntiles; tile += gridDim.x * 4) {
    int arow = tile * 16 + n0;
    ffrag acc[8];
#pragma unroll
    for (int ct = 0; ct < 8; ct++) acc[ct] = (ffrag){0.f, 0.f, 0.f, 0.f};
    for (int rr = 0; rr < 3; rr++) {          // K=384 concat: sum over relations in-MFMA
      const uint32_t* A = P + (size_t)rr * NN * 64;
      bfrag a[4];
#pragma unroll
      for (int t = 0; t < 4; t++)
        a[t] = *(const bfrag*)(A + (size_t)arow * 64 + t * 16 + q * 4);
#pragma unroll
      for (int ct = 0; ct < 8; ct++) {
#pragma unroll
        for (int t = 0; t < 4; t++)
          acc[ct] = __builtin_amdgcn_mfma_f32_16x16x32_bf16(a[t], B[t * 8 + ct], acc[ct], 0, 0, 0);
      }
    }
    int orow = tile * 16 + q * 4;
#pragma unroll
    for (int ct = 0; ct < 8; ct++) {
#pragma unroll
      for (int i = 0; i < 4; i++) {
        float y = acc[ct][i] + bb[ct];
        y = fmaxf(y, 0.f);
        float hv = fmaf(y, gg[ct], b2v[ct]);
        size_t oi = (size_t)(orow + i) * 128 + ct * 16 + n0;
        if (wf32) fout[oi] = hv;
        else hout[oi] = f2bf(hv);
      }
    }
  }
}

extern "C" void kernel_launch(void* const* d_in, const int* in_sizes, int n_in,
                              void* d_out, int out_size, void* d_ws, size_t ws_size,
                              hipStream_t stream) {
  const float* x = (const float*)d_in[0];
  const int* s0 = (const int*)d_in[1]; const int* d0 = (const int*)d_in[2];
  const int* s1 = (const int*)d_in[3]; const int* d1 = (const int*)d_in[4];
  const int* s2 = (const int*)d_in[5]; const int* d2 = (const int*)d_in[6];
  const float* Wg0 = (const float*)d_in[7];
  const float* bg0 = (const float*)d_in[8];
  const float* Wg1 = (const float*)d_in[9];
  const float* bg1 = (const float*)d_in[10];
  const float* Wfc = (const float*)d_in[11];
  const float* bfc = (const float*)d_in[12];
  const float* gamma = (const float*)d_in[13];
  const float* beta = (const float*)d_in[14];
  const float* mean = (const float*)d_in[15];
  const float* var = (const float*)d_in[16];

  char* ws = (char*)d_ws;
  size_t off = 0;
  auto alloc = [&](size_t bytes) { size_t o = off; off = (off + bytes + 255) & ~(size_t)255; return o; };
  size_t o_bh    = alloc((size_t)6 * NBK * 4);
  size_t o_bases = alloc((size_t)6 * (NBK + 1) * 4);
  size_t o_cur   = alloc((size_t)6 * NBK * 4);
  size_t o_sin   = alloc((size_t)3 * NN * 4);
  size_t o_sout  = alloc((size_t)3 * NN * 4);
  size_t o_rp    = alloc((size_t)3 * NNP1 * 4);
  size_t o_col   = alloc((size_t)3 * NE * 4);
  size_t o_wswz  = alloc((size_t)131072 * 2);
  size_t o_cst   = alloc((size_t)768 * 4);
  size_t o_h     = alloc((size_t)NN * 128 * 2);
  size_t o_agg   = alloc((size_t)3 * NN * 128 * 2);
  size_t o_P     = alloc((size_t)3 * NN * 128 * 2);
  (void)ws_size; (void)in_sizes; (void)n_in; (void)out_size;

  uint32_t* bh   = (uint32_t*)(ws + o_bh);
  int* bases     = (int*)(ws + o_bases);
  uint32_t* cur  = (uint32_t*)(ws + o_cur);
  float* s_in    = (float*)(ws + o_sin);
  float* s_out   = (float*)(ws + o_sout);
  int* rowptr    = (int*)(ws + o_rp);
  int* col       = (int*)(ws + o_col);
  uint16_t* wswz = (uint16_t*)(ws + o_wswz);
  float* cst     = (float*)(ws + o_cst);
  uint32_t* h    = (uint32_t*)(ws + o_h);
  uint32_t* agg  = (uint32_t*)(ws + o_agg);
  uint16_t* P    = (uint16_t*)(ws + o_P);
  // pairs/srcs are dead after build; alias them into the agg region (28.8 MB < 76.8 MB)
  uint32_t* pairs = (uint32_t*)(ws + o_agg);
  uint16_t* srcs  = (uint16_t*)(ws + o_agg + (size_t)3 * NE * 4);

  hipMemsetAsync(ws + o_bh, 0, (size_t)6 * NBK * 4, stream);

  k_cast_x<<<2048, 256, 0, stream>>>(x, h);
  k_prep_w<<<512, 256, 0, stream>>>(Wg0, Wg1, Wfc, wswz);
  k_prep_consts<<<1, 256, 0, stream>>>(bg0, bg1, Wfc, bfc, gamma, beta, mean, var, cst);
  k_bhist<<<dim3(NSL, 3), 256, 0, stream>>>(s0, s1, s2, d0, d1, d2, bh);
  k_bscan<<<6, 256, 0, stream>>>(bh, bases, cur, rowptr);
  k_bscatter<<<dim3(NSL, 3), 256, 0, stream>>>(s0, s1, s2, d0, d1, d2, cur, pairs, srcs);
  k_bucket_csr<<<dim3(NBK, 3), 256, 0, stream>>>(pairs, bases, rowptr, s_in, col);
  k_bucket_sout<<<dim3(NBK, 3), 256, 0, stream>>>(srcs, bases, s_out);

  for (int l = 0; l < 2; l++) {
    k_aggregate<<<dim3(25000, 3), 256, 0, stream>>>(h, rowptr, col, s_out, s_in, agg);
    k_gconv_mm<<<dim3(256, 3), 256, 0, stream>>>(agg, (const short*)wswz, 3 * l, P);
    k_fc<<<256, 256, 0, stream>>>((const uint32_t*)P, (const short*)wswz, 6 + l, cst, l,
                                  (uint16_t*)h, (float*)d_out, l);
  }
}

// Round 4
// 747.718 us; speedup vs baseline: 2.1670x; 1.3750x over previous
//
#include <hip/hip_runtime.h>
#include <stdint.h>

#define NN 100000
#define NE 1600000
#define NE4 (NE / 4)
#define NNP1 100008          // rowptr row stride, padded for int4 alignment
#define NBK 196              // node buckets of 512 (100000 -> 196)
#define NSL 64               // edge slices (blocks) per relation for build

typedef __attribute__((ext_vector_type(8))) short bfrag;   // 8 bf16 = 4 VGPRs
typedef __attribute__((ext_vector_type(4))) float ffrag;   // mfma accumulator

__device__ __forceinline__ uint16_t f2bf(float f) {
  uint32_t u = __float_as_uint(f);
  u += 0x7fff + ((u >> 16) & 1);   // round-to-nearest-even
  return (uint16_t)(u >> 16);
}
__device__ __forceinline__ uint32_t pack2(float a, float b) {
  return (uint32_t)f2bf(a) | ((uint32_t)f2bf(b) << 16);
}

// ---------- x (fp32) -> h (bf16, packed pairs) ----------
__global__ void k_cast_x(const float* __restrict__ x, uint32_t* __restrict__ h) {
  int n = NN * 64;
  for (int i = blockIdx.x * blockDim.x + threadIdx.x; i < n; i += gridDim.x * blockDim.x) {
    float2 v = ((const float2*)x)[i];
    h[i] = pack2(v.x, v.y);
  }
}

// ---------- pre-swizzle all 8 weight matrices into MFMA B-fragment order ----------
__global__ void k_prep_w(const float* __restrict__ Wg0, const float* __restrict__ Wg1,
                         const float* __restrict__ Wfc, uint16_t* __restrict__ wswz) {
  int idx = blockIdx.x * 256 + threadIdx.x;          // 0 .. 131071 (8 * 16384)
  int m = idx >> 14;
  int rem = idx & 16383;
  int j = rem & 7;
  int lane = (rem >> 3) & 63;
  int f = rem >> 9;                                   // t*8+ct
  int t = f >> 3, ct = f & 7;
  int k = t * 32 + (lane >> 4) * 8 + j;
  int n = ct * 16 + (lane & 15);
  const float* src = (m < 3) ? (Wg0 + m * 16384)
                   : (m < 6) ? (Wg1 + (m - 3) * 16384)
                             : (Wfc + (m - 6) * 16384);
  wswz[idx] = f2bf(src[k * 128 + n]);
}

// ---------- tiny constants: bias2 = (sum_r bg)@Wfc + bfc ; BN folded to g2,b2 ----------
__global__ void k_prep_consts(const float* __restrict__ bg0, const float* __restrict__ bg1,
                              const float* __restrict__ Wfc, const float* __restrict__ bfc,
                              const float* __restrict__ gamma, const float* __restrict__ beta,
                              const float* __restrict__ mean, const float* __restrict__ var,
                              float* __restrict__ cst) {
  int tid = threadIdx.x;              // 0..255 = l*128 + n
  int l = tid >> 7, n = tid & 127;
  const float* bg = l ? bg1 : bg0;
  float acc = bfc[l * 128 + n];
  for (int k = 0; k < 128; k++) {
    float bsum = bg[k] + bg[128 + k] + bg[256 + k];
    acc += bsum * Wfc[l * 16384 + k * 128 + n];
  }
  cst[tid] = acc;                                    // bias2
  float g = gamma[tid] * rsqrtf(var[tid] + 1e-5f);
  cst[256 + tid] = g;                                // g2
  cst[512 + tid] = beta[tid] - mean[tid] * g;        // b2
}

// ---------- build 1: per-slice LDS bucket histograms, tiny global merge ----------
__global__ void k_bhist(const int* __restrict__ s0, const int* __restrict__ s1,
                        const int* __restrict__ s2, const int* __restrict__ d0,
                        const int* __restrict__ d1, const int* __restrict__ d2,
                        uint32_t* __restrict__ bh) {
  int r = blockIdx.y, blk = blockIdx.x, t = threadIdx.x;
  __shared__ uint32_t hD[NBK], hS[NBK];
  for (int i = t; i < NBK; i += 256) { hD[i] = 0; hS[i] = 0; }
  __syncthreads();
  const int4* sp = (const int4*)((r == 0) ? s0 : (r == 1) ? s1 : s2);
  const int4* dp = (const int4*)((r == 0) ? d0 : (r == 1) ? d1 : d2);
  int base = blk * (NE4 / NSL);
  for (int i = t; i < NE4 / NSL; i += 256) {
    int4 s = sp[base + i];
    int4 d = dp[base + i];
    atomicAdd(&hD[d.x >> 9], 1u); atomicAdd(&hD[d.y >> 9], 1u);
    atomicAdd(&hD[d.z >> 9], 1u); atomicAdd(&hD[d.w >> 9], 1u);
    atomicAdd(&hS[s.x >> 9], 1u); atomicAdd(&hS[s.y >> 9], 1u);
    atomicAdd(&hS[s.z >> 9], 1u); atomicAdd(&hS[s.w >> 9], 1u);
  }
  __syncthreads();
  for (int i = t; i < NBK; i += 256) {
    if (hD[i]) atomicAdd(&bh[r * NBK + i], hD[i]);
    if (hS[i]) atomicAdd(&bh[(3 + r) * NBK + i], hS[i]);
  }
}

// ---------- build 2: exclusive scan of each segment's 196 bucket counts ----------
__global__ void k_bscan(const uint32_t* __restrict__ bh, int* __restrict__ bases,
                        uint32_t* __restrict__ cur, int* __restrict__ rowptr) {
  int seg = blockIdx.x, t = threadIdx.x;     // 256 threads
  int lane = t & 63, wid = t >> 6;
  int v = (t < NBK) ? (int)bh[seg * NBK + t] : 0;
  int x = v;
#pragma unroll
  for (int o = 1; o < 64; o <<= 1) { int y = __shfl_up(x, o); if (lane >= o) x += y; }
  __shared__ int ws[4];
  if (lane == 63) ws[wid] = x;
  __syncthreads();
  int woff = 0;
  for (int i = 0; i < wid; i++) woff += ws[i];
  int incl = woff + x, excl = incl - v;
  if (t < NBK) { bases[seg * (NBK + 1) + t] = excl; cur[seg * NBK + t] = (uint32_t)excl; }
  if (t == 255) bases[seg * (NBK + 1) + NBK] = incl;   // = NE
  if (seg < 3 && t == 0) rowptr[seg * NNP1 + NN] = NE;
}

// ---------- build 3: scatter edges into buckets (block-chunk claims, LDS cursors) ----------
__global__ void k_bscatter(const int* __restrict__ s0, const int* __restrict__ s1,
                           const int* __restrict__ s2, const int* __restrict__ d0,
                           const int* __restrict__ d1, const int* __restrict__ d2,
                           uint32_t* __restrict__ cur, uint32_t* __restrict__ pairs,
                           uint16_t* __restrict__ srcs) {
  int r = blockIdx.y, blk = blockIdx.x, t = threadIdx.x;
  __shared__ uint32_t hD[NBK], hS[NBK];
  for (int i = t; i < NBK; i += 256) { hD[i] = 0; hS[i] = 0; }
  __syncthreads();
  const int4* sp = (const int4*)((r == 0) ? s0 : (r == 1) ? s1 : s2);
  const int4* dp = (const int4*)((r == 0) ? d0 : (r == 1) ? d1 : d2);
  int base = blk * (NE4 / NSL);
  for (int i = t; i < NE4 / NSL; i += 256) {
    int4 s = sp[base + i];
    int4 d = dp[base + i];
    atomicAdd(&hD[d.x >> 9], 1u); atomicAdd(&hD[d.y >> 9], 1u);
    atomicAdd(&hD[d.z >> 9], 1u); atomicAdd(&hD[d.w >> 9], 1u);
    atomicAdd(&hS[s.x >> 9], 1u); atomicAdd(&hS[s.y >> 9], 1u);
    atomicAdd(&hS[s.z >> 9], 1u); atomicAdd(&hS[s.w >> 9], 1u);
  }
  __syncthreads();
  for (int i = t; i < NBK; i += 256) {
    hD[i] = atomicAdd(&cur[r * NBK + i], hD[i]);
    hS[i] = atomicAdd(&cur[(3 + r) * NBK + i], hS[i]);
  }
  __syncthreads();
  uint32_t* pr = pairs + (size_t)r * NE;
  uint16_t* sr = srcs + (size_t)r * NE;
#define SCAT1(S, D) { \
    uint32_t p = atomicAdd(&hD[(D) >> 9], 1u); \
    pr[p] = (uint32_t)(((D) & 511) << 17) | (uint32_t)(S); \
    uint32_t q = atomicAdd(&hS[(S) >> 9], 1u); \
    sr[q] = (uint16_t)((S) & 511); }
  for (int i = t; i < NE4 / NSL; i += 256) {
    int4 s = sp[base + i];
    int4 d = dp[base + i];
    SCAT1(s.x, d.x) SCAT1(s.y, d.y) SCAT1(s.z, d.z) SCAT1(s.w, d.w)
  }
#undef SCAT1
}

// ---------- build 4: per-bucket CSR (rowptr, s_in, col) ----------
__global__ void k_bucket_csr(const uint32_t* __restrict__ pairs, const int* __restrict__ bases,
                             int* __restrict__ rowptr, float* __restrict__ s_in,
                             int* __restrict__ col) {
  int b = blockIdx.x, r = blockIdx.y, t = threadIdx.x;
  int node0 = b << 9;
  int nc = min(512, NN - node0);
  int rb = bases[r * (NBK + 1) + b];
  int m = bases[r * (NBK + 1) + b + 1] - rb;
  __shared__ int cnt[512];
  __shared__ int exc[512];
  __shared__ int ws[4];
  cnt[t] = 0; cnt[t + 256] = 0;
  __syncthreads();
  const uint32_t* pp = pairs + (size_t)r * NE + rb;
  for (int i = t; i < m; i += 256) atomicAdd(&cnt[pp[i] >> 17], 1);
  __syncthreads();
  int v0 = cnt[2 * t], v1 = cnt[2 * t + 1];
  int s = v0 + v1, x = s;
  int lane = t & 63, wid = t >> 6;
#pragma unroll
  for (int o = 1; o < 64; o <<= 1) { int y = __shfl_up(x, o); if (lane >= o) x += y; }
  if (lane == 63) ws[wid] = x;
  __syncthreads();
  int woff = 0;
  for (int i = 0; i < wid; i++) woff += ws[i];
  int e0 = woff + x - s;
  exc[2 * t] = e0;
  exc[2 * t + 1] = e0 + v0;
  __syncthreads();
  for (int i = t; i < nc; i += 256) {
    rowptr[r * NNP1 + node0 + i] = rb + exc[i];
    s_in[r * NN + node0 + i] = rsqrtf((float)(cnt[i] < 1 ? 1 : cnt[i]));
  }
  __syncthreads();
  int* cl = col + (size_t)r * NE + rb;
  for (int i = t; i < m; i += 256) {
    uint32_t e = pp[i];
    int p = atomicAdd(&exc[e >> 17], 1);
    cl[p] = (int)(e & 0x1FFFF);
  }
}

// ---------- build 5: per-bucket out-degree -> s_out ----------
__global__ void k_bucket_sout(const uint16_t* __restrict__ srcs, const int* __restrict__ bases,
                              float* __restrict__ s_out) {
  int b = blockIdx.x, r = blockIdx.y, t = threadIdx.x;
  int node0 = b << 9;
  int nc = min(512, NN - node0);
  int rb = bases[(3 + r) * (NBK + 1) + b];
  int m = bases[(3 + r) * (NBK + 1) + b + 1] - rb;
  __shared__ int cnt[512];
  cnt[t] = 0; cnt[t + 256] = 0;
  __syncthreads();
  const uint16_t* pp = srcs + (size_t)r * NE + rb;
  for (int i = t; i < m; i += 256) atomicAdd(&cnt[pp[i]], 1);
  __syncthreads();
  for (int i = t; i < nc; i += 256)
    s_out[r * NN + node0 + i] = rsqrtf((float)(cnt[i] < 1 ? 1 : cnt[i]));
}

// ---------- aggregation: agg_r[n] = rsqrt(deg_in) * sum_e rsqrt(deg_out[src]) * h[src] ----------
// one wave per dst node; lane covers feature pair (2*lane, 2*lane+1).
// Edge id/weight broadcast via readlane (scalar) -> scalar-base row gathers, 8 in flight.
__global__ void k_aggregate(const uint32_t* __restrict__ h, const int* __restrict__ rowptr,
                            const int* __restrict__ col, const float* __restrict__ s_out,
                            const float* __restrict__ s_in, uint32_t* __restrict__ agg) {
  int r = blockIdx.y;
  int node = blockIdx.x * 4 + (threadIdx.x >> 6);
  int lane = threadIdx.x & 63;
  const int* rp = rowptr + r * NNP1;
  int beg = rp[node], end = rp[node + 1];
  const int* cl = col + (size_t)r * NE;
  const float* so = s_out + r * NN;
  float a0 = 0.f, a1 = 0.f;
  for (int base = beg; base < end; base += 64) {
    int idx = base + lane;
    int sv = 0; int wb = 0;
    if (idx < end) { sv = cl[idx]; wb = __float_as_int(so[sv]); }
    int cnt = min(64, end - base);
    int cnt8 = (cnt + 7) & ~7;     // lanes >= cnt hold s=0,w=0 -> harmless row-0 gathers
    for (int j = 0; j < cnt8; j += 8) {
      uint32_t hv[8]; float ww[8];
#pragma unroll
      for (int u = 0; u < 8; u++) {
        int ss = __builtin_amdgcn_readlane(sv, j + u);
        ww[u] = __int_as_float(__builtin_amdgcn_readlane(wb, j + u));
        hv[u] = h[(size_t)ss * 64 + lane];
      }
#pragma unroll
      for (int u = 0; u < 8; u++) {
        a0 = fmaf(__uint_as_float(hv[u] << 16), ww[u], a0);
        a1 = fmaf(__uint_as_float(hv[u] & 0xffff0000u), ww[u], a1);
      }
    }
  }
  float sc = s_in[r * NN + node];
  agg[((size_t)r * NN + node) * 64 + lane] = pack2(a0 * sc, a1 * sc);
}

// ---------- P_r = agg_r @ Wg[l][r]   (bf16 MFMA, wave-held B frags) ----------
__global__ __launch_bounds__(256, 2) void k_gconv_mm(const uint32_t* __restrict__ agg,
                                                     const short* __restrict__ wswz,
                                                     int wbase, uint16_t* __restrict__ P) {
  int r = blockIdx.y;
  int lane = threadIdx.x & 63;
  int wid = threadIdx.x >> 6;
  int q = lane >> 4, n0 = lane & 15;
  const bfrag* wp = (const bfrag*)(wswz + (size_t)(wbase + r) * 16384);
  bfrag B[32];
#pragma unroll
  for (int f = 0; f < 32; f++) B[f] = wp[f * 64 + lane];
  const uint32_t* A = agg + (size_t)r * NN * 64;
  uint16_t* Pr = P + (size_t)r * NN * 128;
  const int ntiles = NN / 16;   // 6250, exact
  for (int tile = blockIdx.x * 4 + wid; tile < ntiles; tile += gridDim.x * 4) {
    int arow = tile * 16 + n0;
    bfrag a[4];
#pragma unroll
    for (int t = 0; t < 4; t++)
      a[t] = *(const bfrag*)(A + (size_t)arow * 64 + t * 16 + q * 4);
    ffrag acc[8];
#pragma unroll
    for (int ct = 0; ct < 8; ct++) {
      ffrag c = {0.f, 0.f, 0.f, 0.f};
#pragma unroll
      for (int t = 0; t < 4; t++)
        c = __builtin_amdgcn_mfma_f32_16x16x32_bf16(a[t], B[t * 8 + ct], c, 0, 0, 0);
      acc[ct] = c;
    }
    int orow = tile * 16 + q * 4;
#pragma unroll
    for (int ct = 0; ct < 8; ct++)
#pragma unroll
      for (int i = 0; i < 4; i++)
        Pr[(size_t)(orow + i) * 128 + ct * 16 + n0] = f2bf(acc[ct][i]);
  }
}

// ---------- FC: out = relu([P0|P1|P2] @ [Wfc;Wfc;Wfc] + bias2); BN folded ----------
__global__ __launch_bounds__(256, 2) void k_fc(const uint32_t* __restrict__ P,
                                               const short* __restrict__ wswz, int m,
                                               const float* __restrict__ cst, int l,
                                               uint16_t* __restrict__ hout,
                                               float* __restrict__ fout, int wf32) {
  int lane = threadIdx.x & 63;
  int wid = threadIdx.x >> 6;
  int q = lane >> 4, n0 = lane & 15;
  const bfrag* wp = (const bfrag*)(wswz + (size_t)m * 16384);
  bfrag B[32];
#pragma unroll
  for (int f = 0; f < 32; f++) B[f] = wp[f * 64 + lane];
  float bb[8], gg[8], b2v[8];
#pragma unroll
  for (int ct = 0; ct < 8; ct++) {
    int c = l * 128 + ct * 16 + n0;
    bb[ct] = cst[c];
    gg[ct] = cst[256 + c];
    b2v[ct] = cst[512 + c];
  }
  const int ntiles = NN / 16;
  for (int tile = blockIdx.x * 4 + wid; tile < ntiles; tile += gridDim.x * 4) {
    int arow = tile * 16 + n0;
    ffrag acc[8];
#pragma unroll
    for (int ct = 0; ct < 8; ct++) acc[ct] = (ffrag){0.f, 0.f, 0.f, 0.f};
    for (int rr = 0; rr < 3; rr++) {          // K=384 concat: sum over relations in-MFMA
      const uint32_t* A = P + (size_t)rr * NN * 64;
      bfrag a[4];
#pragma unroll
      for (int t = 0; t < 4; t++)
        a[t] = *(const bfrag*)(A + (size_t)arow * 64 + t * 16 + q * 4);
#pragma unroll
      for (int ct = 0; ct < 8; ct++) {
#pragma unroll
        for (int t = 0; t < 4; t++)
          acc[ct] = __builtin_amdgcn_mfma_f32_16x16x32_bf16(a[t], B[t * 8 + ct], acc[ct], 0, 0, 0);
      }
    }
    int orow = tile * 16 + q * 4;
#pragma unroll
    for (int ct = 0; ct < 8; ct++) {
#pragma unroll
      for (int i = 0; i < 4; i++) {
        float y = acc[ct][i] + bb[ct];
        y = fmaxf(y, 0.f);
        float hv = fmaf(y, gg[ct], b2v[ct]);
        size_t oi = (size_t)(orow + i) * 128 + ct * 16 + n0;
        if (wf32) fout[oi] = hv;
        else hout[oi] = f2bf(hv);
      }
    }
  }
}

extern "C" void kernel_launch(void* const* d_in, const int* in_sizes, int n_in,
                              void* d_out, int out_size, void* d_ws, size_t ws_size,
                              hipStream_t stream) {
  const float* x = (const float*)d_in[0];
  const int* s0 = (const int*)d_in[1]; const int* d0 = (const int*)d_in[2];
  const int* s1 = (const int*)d_in[3]; const int* d1 = (const int*)d_in[4];
  const int* s2 = (const int*)d_in[5]; const int* d2 = (const int*)d_in[6];
  const float* Wg0 = (const float*)d_in[7];
  const float* bg0 = (const float*)d_in[8];
  const float* Wg1 = (const float*)d_in[9];
  const float* bg1 = (const float*)d_in[10];
  const float* Wfc = (const float*)d_in[11];
  const float* bfc = (const float*)d_in[12];
  const float* gamma = (const float*)d_in[13];
  const float* beta = (const float*)d_in[14];
  const float* mean = (const float*)d_in[15];
  const float* var = (const float*)d_in[16];

  char* ws = (char*)d_ws;
  size_t off = 0;
  auto alloc = [&](size_t bytes) { size_t o = off; off = (off + bytes + 255) & ~(size_t)255; return o; };
  size_t o_bh    = alloc((size_t)6 * NBK * 4);
  size_t o_bases = alloc((size_t)6 * (NBK + 1) * 4);
  size_t o_cur   = alloc((size_t)6 * NBK * 4);
  size_t o_sin   = alloc((size_t)3 * NN * 4);
  size_t o_sout  = alloc((size_t)3 * NN * 4);
  size_t o_rp    = alloc((size_t)3 * NNP1 * 4);
  size_t o_col   = alloc((size_t)3 * NE * 4);
  size_t o_wswz  = alloc((size_t)131072 * 2);
  size_t o_cst   = alloc((size_t)768 * 4);
  size_t o_h     = alloc((size_t)NN * 128 * 2);
  size_t o_agg   = alloc((size_t)3 * NN * 128 * 2);
  size_t o_P     = alloc((size_t)3 * NN * 128 * 2);
  (void)ws_size; (void)in_sizes; (void)n_in; (void)out_size;

  uint32_t* bh   = (uint32_t*)(ws + o_bh);
  int* bases     = (int*)(ws + o_bases);
  uint32_t* cur  = (uint32_t*)(ws + o_cur);
  float* s_in    = (float*)(ws + o_sin);
  float* s_out   = (float*)(ws + o_sout);
  int* rowptr    = (int*)(ws + o_rp);
  int* col       = (int*)(ws + o_col);
  uint16_t* wswz = (uint16_t*)(ws + o_wswz);
  float* cst     = (float*)(ws + o_cst);
  uint32_t* h    = (uint32_t*)(ws + o_h);
  uint32_t* agg  = (uint32_t*)(ws + o_agg);
  uint16_t* P    = (uint16_t*)(ws + o_P);
  // pairs/srcs are dead after build; alias them into the agg region (28.8 MB < 76.8 MB)
  uint32_t* pairs = (uint32_t*)(ws + o_agg);
  uint16_t* srcs  = (uint16_t*)(ws + o_agg + (size_t)3 * NE * 4);

  hipMemsetAsync(ws + o_bh, 0, (size_t)6 * NBK * 4, stream);

  k_cast_x<<<2048, 256, 0, stream>>>(x, h);
  k_prep_w<<<512, 256, 0, stream>>>(Wg0, Wg1, Wfc, wswz);
  k_prep_consts<<<1, 256, 0, stream>>>(bg0, bg1, Wfc, bfc, gamma, beta, mean, var, cst);
  k_bhist<<<dim3(NSL, 3), 256, 0, stream>>>(s0, s1, s2, d0, d1, d2, bh);
  k_bscan<<<6, 256, 0, stream>>>(bh, bases, cur, rowptr);
  k_bscatter<<<dim3(NSL, 3), 256, 0, stream>>>(s0, s1, s2, d0, d1, d2, cur, pairs, srcs);
  k_bucket_csr<<<dim3(NBK, 3), 256, 0, stream>>>(pairs, bases, rowptr, s_in, col);
  k_bucket_sout<<<dim3(NBK, 3), 256, 0, stream>>>(srcs, bases, s_out);

  for (int l = 0; l < 2; l++) {
    k_aggregate<<<dim3(25000, 3), 256, 0, stream>>>(h, rowptr, col, s_out, s_in, agg);
    k_gconv_mm<<<dim3(256, 3), 256, 0, stream>>>(agg, (const short*)wswz, 3 * l, P);
    k_fc<<<256, 256, 0, stream>>>((const uint32_t*)P, (const short*)wswz, 6 + l, cst, l,
                                  (uint16_t*)h, (float*)d_out, l);
  }
}